// Round 17
// baseline (30.476 us; speedup 1.0000x reference)
//
#include <hip/hip_runtime.h>

typedef float f32x4 __attribute__((ext_vector_type(4)));

#define VL_EPS  1e-4f
#define VL_SEP  0.01f
#define VL_NEPS 1e-12f

// Moller-style interval endpoints, exactly mirroring the reference's
// 3-way branch select. Returns (lo, hi).
__device__ __forceinline__ void vl_intervals(float p0, float p1, float p2,
                                             float d0, float d1, float d2,
                                             float& lo, float& hi) {
  bool c1 = (d0 * d1) > 0.0f;
  bool c2 = (!c1) && ((d0 * d2) > 0.0f);
  float a0, a1, a2, e0, e1, e2;
  if (c1)      { a0 = p2; a1 = p0; a2 = p1; e0 = d2; e1 = d0; e2 = d1; }
  else if (c2) { a0 = p1; a1 = p0; a2 = p2; e0 = d1; e1 = d0; e2 = d2; }
  else         { a0 = p0; a1 = p1; a2 = p2; e0 = d0; e1 = d1; e2 = d2; }
  float i0 = a0 + (a1 - a0) * (e0 / (e0 - e1 + VL_EPS));
  float i1 = a0 + (a2 - a0) * (e0 / (e0 - e2 + VL_EPS));
  lo = fminf(i0, i1);
  hi = fmaxf(i0, i1);
}

// Rare-path tail: identical FP sequence to the validated kernel.
__device__ __forceinline__ int vl_tail(
    float iu0x, float iu0y, float iu0z,
    float iu1x, float iu1y, float iu1z,
    float iu2x, float iu2y, float iu2z,
    float nxi, float nyi, float nzi,
    float ju0x, float ju0y, float ju0z,
    float ju1x, float ju1y, float ju1z,
    float ju2x, float ju2y, float ju2z,
    float nxj, float nyj, float nzj,
    float dij0, float dij1, float dij2,
    float dji0, float dji1, float dji2,
    int gi, int gj) {
  const float cx = nyi * nzj - nzi * nyj;
  const float cy = nzi * nxj - nxi * nzj;
  const float cz = nxi * nyj - nyi * nxj;
  const float nrm = sqrtf(cx * cx + cy * cy + cz * cz);
  const float inv = 1.0f / fmaxf(nrm, VL_NEPS);
  const float dx = cx * inv, dy = cy * inv, dz = cz * inv;

  const float pa0 = dx * ju0x + dy * ju0y + dz * ju0z;
  const float pa1 = dx * ju1x + dy * ju1y + dz * ju1z;
  const float pa2 = dx * ju2x + dy * ju2y + dz * ju2z;
  const float pb0 = dx * iu0x + dy * iu0y + dz * iu0z;
  const float pb1 = dx * iu1x + dy * iu1y + dz * iu1z;
  const float pb2 = dx * iu2x + dy * iu2y + dz * iu2z;

  float aLo, aHi, bLo, bHi;
  vl_intervals(pa0, pa1, pa2, dij0, dij1, dij2, aLo, aHi);
  vl_intervals(pb0, pb1, pb2, dji0, dji1, dji2, bLo, bHi);

  bool sep_;
  if (gi < gj) sep_ = (aHi <= bLo + VL_SEP) || (bHi <= aLo + VL_SEP);
  else         sep_ = false;  // diagonal never killed (triu k=1)

  return sep_ ? 0 : 1;
}

// Pre-gather: SoA gat[c][Fp], c = 0..12 (u0.xyz u1.xyz u2.xyz n.xyz d1).
// Pad faces [F, Fp) are zeroed -> they can never pass the plane test
// (0 + EPS <= 0 is false), so downstream needs no bounds checks.
__global__ __launch_bounds__(256) void vl_gather(const float* __restrict__ verts,
                                                 const float* __restrict__ fnorm,
                                                 const int*   __restrict__ faces,
                                                 float* __restrict__ gat,
                                                 int F, int Fp) {
  const int f = blockIdx.x * 256 + threadIdx.x;
  if (f >= Fp) return;
  float v[13];
#pragma unroll
  for (int c = 0; c < 13; ++c) v[c] = 0.0f;
  if (f < F) {
    const int va = faces[3 * f + 0];
    const int vb = faces[3 * f + 1];
    const int vc = faces[3 * f + 2];
    v[0] = verts[3 * va + 0]; v[1]  = verts[3 * va + 1]; v[2]  = verts[3 * va + 2];
    v[3] = verts[3 * vb + 0]; v[4]  = verts[3 * vb + 1]; v[5]  = verts[3 * vb + 2];
    v[6] = verts[3 * vc + 0]; v[7]  = verts[3 * vc + 1]; v[8]  = verts[3 * vc + 2];
    v[9] = fnorm[3 * f + 0];  v[10] = fnorm[3 * f + 1]; v[11] = fnorm[3 * f + 2];
    v[12] = -(v[0] * v[9] + v[1] * v[10] + v[2] * v[11]);  // d1
  }
#pragma unroll
  for (int c = 0; c < 13; ++c) gat[c * Fp + f] = v[c];
}

// Triangular per-pair kernel, LDS-staging-free: i-attrs via coalesced L2
// loads, j-attrs via wave-uniform (readfirstlane-based -> scalar-path)
// loads. LDS holds only the ring queue and the per-tile counters.
__global__ __launch_bounds__(256) void vl_pair(const float* __restrict__ gat,
                                               float* __restrict__ partial,
                                               int F, int Fp) {
  __shared__ unsigned short qbuf[4][256];  // per-wave ring queue of (ii<<6)|jj
  __shared__ int srowI[64];                // per-i keep counts (i-tile)
  __shared__ int srowJ[64];                // per-j keep counts (j-tile)
  __shared__ float sred[256];

  const int t    = threadIdx.x;
  const int lane = t & 63;
  const int w    = t >> 6;

  // ---- decode linear block id -> triangular (bx, by), bx <= by ----
  const int k = blockIdx.x;
  int by = (int)((sqrtf(8.0f * (float)k + 1.0f) - 1.0f) * 0.5f);
  while ((by + 1) * (by + 2) / 2 <= k) ++by;   // integer fix-up (exact)
  while (by * (by + 1) / 2 > k) --by;
  const int bx = k - by * (by + 1) / 2;
  const int bi = bx * 64;                      // i-tile base (<= bj)
  const int bj = by * 64;                      // j-tile base
  const bool dg = (bx == by);

  if (t < 64) { srowI[t] = 0; srowJ[t] = 0; }
  __syncthreads();

  // ---- per-thread i-face registers: 13 coalesced loads ----
  const int ii = lane;
  const int fi = bi + ii;
  const float iu0x = gat[0 * Fp + fi], iu0y = gat[1 * Fp + fi], iu0z = gat[2 * Fp + fi];
  const float iu1x = gat[3 * Fp + fi], iu1y = gat[4 * Fp + fi], iu1z = gat[5 * Fp + fi];
  const float iu2x = gat[6 * Fp + fi], iu2y = gat[7 * Fp + fi], iu2z = gat[8 * Fp + fi];
  const float nxi  = gat[9 * Fp + fi], nyi  = gat[10 * Fp + fi], nzi = gat[11 * Fp + fi];
  const float d1i  = gat[12 * Fp + fi];

  unsigned short* qb = qbuf[w];
  int qtail = 0, qhead = 0;  // wave-uniform (derived from ballots only)

  // Dense drain: nd queued pairs processed by nd lanes, full tail math.
  auto drain = [&](int nd) {
    if (lane < nd) {
      const int e  = qb[(qhead + lane) & 255];
      const int qi = bi + (e >> 6);
      const int qj = bj + (e & 63);
      const float A0x = gat[0 * Fp + qi], A0y = gat[1 * Fp + qi], A0z = gat[2 * Fp + qi];
      const float A1x = gat[3 * Fp + qi], A1y = gat[4 * Fp + qi], A1z = gat[5 * Fp + qi];
      const float A2x = gat[6 * Fp + qi], A2y = gat[7 * Fp + qi], A2z = gat[8 * Fp + qi];
      const float Anx = gat[9 * Fp + qi], Any = gat[10 * Fp + qi], Anz = gat[11 * Fp + qi];
      const float Ad  = gat[12 * Fp + qi];
      const float B0x = gat[0 * Fp + qj], B0y = gat[1 * Fp + qj], B0z = gat[2 * Fp + qj];
      const float B1x = gat[3 * Fp + qj], B1y = gat[4 * Fp + qj], B1z = gat[5 * Fp + qj];
      const float B2x = gat[6 * Fp + qj], B2y = gat[7 * Fp + qj], B2z = gat[8 * Fp + qj];
      const float Bnx = gat[9 * Fp + qj], Bny = gat[10 * Fp + qj], Bnz = gat[11 * Fp + qj];
      const float Bd  = gat[12 * Fp + qj];
      // recompute plane distances, identical scalar expressions
      const float dij0 = Anx * B0x + Any * B0y + Anz * B0z + Ad;
      const float dij1 = Anx * B1x + Any * B1y + Anz * B1z + Ad;
      const float dij2 = Anx * B2x + Any * B2y + Anz * B2z + Ad;
      const float dji0 = Bnx * A0x + Bny * A0y + Bnz * A0z + Bd;
      const float dji1 = Bnx * A1x + Bny * A1y + Bnz * A1z + Bd;
      const float dji2 = Bnx * A2x + Bny * A2y + Bnz * A2z + Bd;
      const int kk = vl_tail(A0x, A0y, A0z, A1x, A1y, A1z, A2x, A2y, A2z,
                             Anx, Any, Anz,
                             B0x, B0y, B0z, B1x, B1y, B1z, B2x, B2y, B2z,
                             Bnx, Bny, Bnz,
                             dij0, dij1, dij2, dji0, dji1, dji2,
                             qi, qj);
      if (kk) {
        const int li = qi - bi, lj = qj - bj;
        atomicAdd(&srowI[li], 1);                       // credit row[i]
        if (!(dg && li == lj))                          // self-pair: once
          atomicAdd(dg ? &srowI[lj] : &srowJ[lj], 1);   // credit row[j]
      }
    }
    qhead += nd;
  };

  // ---- phase 1: branchless 4-wide packed plane tests (4 x 4 j's) ----
  const unsigned long long lt = (1ULL << lane) - 1ULL;
#pragma unroll 2
  for (int s = 0; s < 4; ++s) {
    const int jj = (w << 2) + (s << 4);   // multiple of 4 -> 16B-aligned
    // wave-uniform base -> scalar-path loads
    const int jb = __builtin_amdgcn_readfirstlane(bj + jj);

    const f32x4 ju0x = *(const f32x4*)(gat + 0 * Fp + jb);
    const f32x4 ju0y = *(const f32x4*)(gat + 1 * Fp + jb);
    const f32x4 ju0z = *(const f32x4*)(gat + 2 * Fp + jb);
    const f32x4 ju1x = *(const f32x4*)(gat + 3 * Fp + jb);
    const f32x4 ju1y = *(const f32x4*)(gat + 4 * Fp + jb);
    const f32x4 ju1z = *(const f32x4*)(gat + 5 * Fp + jb);
    const f32x4 ju2x = *(const f32x4*)(gat + 6 * Fp + jb);
    const f32x4 ju2y = *(const f32x4*)(gat + 7 * Fp + jb);
    const f32x4 ju2z = *(const f32x4*)(gat + 8 * Fp + jb);
    const f32x4 nxj  = *(const f32x4*)(gat + 9 * Fp + jb);
    const f32x4 nyj  = *(const f32x4*)(gat + 10 * Fp + jb);
    const f32x4 nzj  = *(const f32x4*)(gat + 11 * Fp + jb);
    const f32x4 d1j  = *(const f32x4*)(gat + 12 * Fp + jb);

    // packed plane distances, all 4 j sub-lanes
    const f32x4 dij0 = nxi * ju0x + nyi * ju0y + nzi * ju0z + d1i;
    const f32x4 dij1 = nxi * ju1x + nyi * ju1y + nzi * ju1z + d1i;
    const f32x4 dij2 = nxi * ju2x + nyi * ju2y + nzi * ju2z + d1i;
    const f32x4 dji0 = nxj * iu0x + nyj * iu0y + nzj * iu0z + d1j;
    const f32x4 dji1 = nxj * iu1x + nyj * iu1y + nzj * iu1z + d1j;
    const f32x4 dji2 = nxj * iu2x + nyj * iu2y + nzj * iu2z + d1j;

    // exact monotone form of the all-pos / all-neg tests, both directions
    const f32x4 mnv = __builtin_elementwise_max(
        __builtin_elementwise_min(__builtin_elementwise_min(dij0, dij1), dij2),
        __builtin_elementwise_min(__builtin_elementwise_min(dji0, dji1), dji2));
    const f32x4 mxv = __builtin_elementwise_min(
        __builtin_elementwise_max(__builtin_elementwise_max(dij0, dij1), dij2),
        __builtin_elementwise_max(__builtin_elementwise_max(dji0, dji1), dji2));

    bool sv[4];
#pragma unroll
    for (int q = 0; q < 4; ++q) {
      sv[q] = (mnv[q] + VL_EPS <= 0.0f) && (mxv[q] - VL_EPS >= 0.0f);
      if (dg) sv[q] = sv[q] && (ii <= jj + q);   // diagonal: ii <= jj only
    }

    // pushes in j-order; ring-safety: drain-check after every 2 pushes
    const unsigned long long m0 = __ballot(sv[0]);
    const unsigned long long m1 = __ballot(sv[1]);
    if (m0 | m1) {
      const int n0 = __popcll(m0);
      if (sv[0]) qb[(qtail + __popcll(m0 & lt)) & 255] =
                     (unsigned short)((ii << 6) | jj);
      if (sv[1]) qb[(qtail + n0 + __popcll(m1 & lt)) & 255] =
                     (unsigned short)((ii << 6) | (jj + 1));
      qtail += n0 + __popcll(m1);
      while (qtail - qhead >= 64) drain(64);
    }
    const unsigned long long m2 = __ballot(sv[2]);
    const unsigned long long m3 = __ballot(sv[3]);
    if (m2 | m3) {
      const int n2 = __popcll(m2);
      if (sv[2]) qb[(qtail + __popcll(m2 & lt)) & 255] =
                     (unsigned short)((ii << 6) | (jj + 2));
      if (sv[3]) qb[(qtail + n2 + __popcll(m3 & lt)) & 255] =
                     (unsigned short)((ii << 6) | (jj + 3));
      qtail += n2 + __popcll(m3);
      while (qtail - qhead >= 64) drain(64);
    }
  }
  if (qtail > qhead) drain(qtail - qhead);

  // ---- epilogue: block-local partial loss, fixed-order reduce ----
  __syncthreads();
  float val = 0.0f;
  if (t < 64) {
    // w[f] = x(v0) + 2*x(v2); pad entries are 0 and srow is 0 there.
    val = (gat[0 * Fp + bi + t] + 2.0f * gat[6 * Fp + bi + t]) * (float)srowI[t];
  } else if (t < 128 && !dg) {
    const int l = t - 64;
    val = (gat[0 * Fp + bj + l] + 2.0f * gat[6 * Fp + bj + l]) * (float)srowJ[l];
  }
  sred[t] = val;
  __syncthreads();
#pragma unroll
  for (int r = 128; r > 0; r >>= 1) {
    if (t < r) sred[t] += sred[t + r];
    __syncthreads();
  }
  if (t == 0) partial[k] = sred[0];
}

// Final fixed-order reduction over per-block partials: loss = (sum)/3.
__global__ __launch_bounds__(256) void vl_reduce(const float* __restrict__ partial,
                                                 int n, float* __restrict__ out) {
  __shared__ float s[256];
  const int t = threadIdx.x;
  float acc = 0.0f;
  for (int b = t; b < n; b += 256) acc += partial[b];
  s[t] = acc;
  __syncthreads();
  for (int r = 128; r > 0; r >>= 1) {
    if (t < r) s[t] += s[t + r];
    __syncthreads();
  }
  if (t == 0) out[0] = s[0] / 3.0f;
}

extern "C" void kernel_launch(void* const* d_in, const int* in_sizes, int n_in,
                              void* d_out, int out_size, void* d_ws, size_t ws_size,
                              hipStream_t stream) {
  const float* verts = (const float*)d_in[0];   // (1, V, 3) f32
  const float* fnorm = (const float*)d_in[1];   // (1, F, 3) f32
  const int*   faces = (const int*)d_in[2];     // (F, 3) int32
  const int F = in_sizes[1] / 3;

  const int NB = (F + 63) / 64;
  const int Fp = NB * 64;                        // padded face count
  float* gat     = (float*)d_ws;                 // 13 * Fp floats (SoA)
  float* partial = gat + 13 * Fp;                // nblk floats (no zeroing)

  const int nblk = NB * (NB + 1) / 2;            // triangular tile pairs
  vl_gather<<<(Fp + 255) / 256, 256, 0, stream>>>(verts, fnorm, faces, gat, F, Fp);
  vl_pair<<<nblk, 256, 0, stream>>>(gat, partial, F, Fp);
  vl_reduce<<<1, 256, 0, stream>>>(partial, nblk, (float*)d_out);
}

// Round 18
// 21.938 us; speedup vs baseline: 1.3892x; 1.3892x over previous
//
#include <hip/hip_runtime.h>

typedef float f32x4 __attribute__((ext_vector_type(4)));

#define VL_EPS  1e-4f
#define VL_SEP  0.01f
#define VL_NEPS 1e-12f

// Moller-style interval endpoints, exactly mirroring the reference's
// 3-way branch select. Returns (lo, hi).
__device__ __forceinline__ void vl_intervals(float p0, float p1, float p2,
                                             float d0, float d1, float d2,
                                             float& lo, float& hi) {
  bool c1 = (d0 * d1) > 0.0f;
  bool c2 = (!c1) && ((d0 * d2) > 0.0f);
  float a0, a1, a2, e0, e1, e2;
  if (c1)      { a0 = p2; a1 = p0; a2 = p1; e0 = d2; e1 = d0; e2 = d1; }
  else if (c2) { a0 = p1; a1 = p0; a2 = p2; e0 = d1; e1 = d0; e2 = d2; }
  else         { a0 = p0; a1 = p1; a2 = p2; e0 = d0; e1 = d1; e2 = d2; }
  float i0 = a0 + (a1 - a0) * (e0 / (e0 - e1 + VL_EPS));
  float i1 = a0 + (a2 - a0) * (e0 / (e0 - e2 + VL_EPS));
  lo = fminf(i0, i1);
  hi = fmaxf(i0, i1);
}

// Rare-path tail: cross product, interval overlap, separation test.
// Identical FP sequence to the validated scalar kernel (exact sqrt/div).
// Only gi<gj and gi==gj can occur in the triangular scheme.
__device__ __forceinline__ int vl_tail(
    float iu0x, float iu0y, float iu0z,
    float iu1x, float iu1y, float iu1z,
    float iu2x, float iu2y, float iu2z,
    float nxi, float nyi, float nzi,
    float ju0x, float ju0y, float ju0z,
    float ju1x, float ju1y, float ju1z,
    float ju2x, float ju2y, float ju2z,
    float nxj, float nyj, float nzj,
    float dij0, float dij1, float dij2,
    float dji0, float dji1, float dji2,
    int gi, int gj) {
  // D = normalize(cross(n_i, n_j)) (clamped norm)
  const float cx = nyi * nzj - nzi * nyj;
  const float cy = nzi * nxj - nxi * nzj;
  const float cz = nxi * nyj - nyi * nxj;
  const float nrm = sqrtf(cx * cx + cy * cy + cz * cz);
  const float inv = 1.0f / fmaxf(nrm, VL_NEPS);
  const float dx = cx * inv, dy = cy * inv, dz = cz * inv;

  // A-intervals: (Up[i,j,k], DU[i,j,k]); B-intervals: (-Up[j,i,k], DU[j,i,k])
  const float pa0 = dx * ju0x + dy * ju0y + dz * ju0z;
  const float pa1 = dx * ju1x + dy * ju1y + dz * ju1z;
  const float pa2 = dx * ju2x + dy * ju2y + dz * ju2z;
  const float pb0 = dx * iu0x + dy * iu0y + dz * iu0z;
  const float pb1 = dx * iu1x + dy * iu1y + dz * iu1z;
  const float pb2 = dx * iu2x + dy * iu2y + dz * iu2z;

  float aLo, aHi, bLo, bHi;
  vl_intervals(pa0, pa1, pa2, dij0, dij1, dij2, aLo, aHi);
  vl_intervals(pb0, pb1, pb2, dji0, dji1, dji2, bLo, bHi);

  bool sep_;
  if (gi < gj) sep_ = (aHi <= bLo + VL_SEP) || (bHi <= aLo + VL_SEP);
  else         sep_ = false;  // diagonal never killed (triu k=1)

  return sep_ ? 0 : 1;
}

// Triangular per-pair kernel: one block per unordered tile pair (bx<=by),
// 64x64 faces per tile, 256 threads (4 waves).
// Wave w owns all 64 i's x its 16 j's (jj = 4w + 16s + {0..3}, s=0..3).
// Phase 1: branchless 4-wide packed plane tests (ds_read_b128 j-attrs);
// survivors -> per-wave LDS ring queue. Drain: dense tail math; kept pairs
// credit LDS counters for BOTH tiles. Epilogue: block-local float partial
// loss (w[f] = x(v0)+2*x(v2) comes straight from the staged LDS tile),
// fixed-order tree reduce, one global store per block. No global atomics,
// no workspace zeroing needed.
__global__ __launch_bounds__(256) void vl_pair(const float* __restrict__ verts,
                                               const float* __restrict__ fnorm,
                                               const int*   __restrict__ faces,
                                               float* __restrict__ partial,
                                               int F) {
  __shared__ float sI[13 * 64];
  __shared__ float sJ[13 * 64];
  __shared__ unsigned short qbuf[4][256];  // per-wave ring queue of (ii<<6)|jj
  __shared__ int srowI[64];                // per-i keep counts (i-tile)
  __shared__ int srowJ[64];                // per-j keep counts (j-tile)
  __shared__ float sred[256];

  const int t    = threadIdx.x;
  const int lane = t & 63;
  const int w    = t >> 6;

  // ---- decode linear block id -> triangular (bx, by), bx <= by ----
  const int k = blockIdx.x;
  int by = (int)((sqrtf(8.0f * (float)k + 1.0f) - 1.0f) * 0.5f);
  while ((by + 1) * (by + 2) / 2 <= k) ++by;   // integer fix-up (exact)
  while (by * (by + 1) / 2 > k) --by;
  const int bx = k - by * (by + 1) / 2;
  const int bi = bx * 64;                      // i-tile base (<= bj)
  const int bj = by * 64;                      // j-tile base
  const bool dg = (bx == by);

  // ---- stage the two 64-face tiles into LDS (gather + compute d1) ----
  if (t < 128) {
    const bool isI = (t < 64);
    const int  lf  = t & 63;
    const int  f   = (isI ? bi : bj) + lf;
    float* dst = isI ? sI : sJ;
    float v[13];
#pragma unroll
    for (int c = 0; c < 13; ++c) v[c] = 0.0f;
    if (f < F) {
      const int va = faces[3 * f + 0];
      const int vb = faces[3 * f + 1];
      const int vc = faces[3 * f + 2];
      v[0] = verts[3 * va + 0]; v[1]  = verts[3 * va + 1]; v[2]  = verts[3 * va + 2];
      v[3] = verts[3 * vb + 0]; v[4]  = verts[3 * vb + 1]; v[5]  = verts[3 * vb + 2];
      v[6] = verts[3 * vc + 0]; v[7]  = verts[3 * vc + 1]; v[8]  = verts[3 * vc + 2];
      v[9] = fnorm[3 * f + 0];  v[10] = fnorm[3 * f + 1]; v[11] = fnorm[3 * f + 2];
      v[12] = -(v[0] * v[9] + v[1] * v[10] + v[2] * v[11]);  // d1
    }
#pragma unroll
    for (int c = 0; c < 13; ++c) dst[c * 64 + lf] = v[c];
  }
  if (t < 64) { srowI[t] = 0; srowJ[t] = 0; }
  __syncthreads();

  // ---- per-thread i-face registers ----
  const int ii = lane;
  const float iu0x = sI[0 * 64 + ii], iu0y = sI[1 * 64 + ii], iu0z = sI[2 * 64 + ii];
  const float iu1x = sI[3 * 64 + ii], iu1y = sI[4 * 64 + ii], iu1z = sI[5 * 64 + ii];
  const float iu2x = sI[6 * 64 + ii], iu2y = sI[7 * 64 + ii], iu2z = sI[8 * 64 + ii];
  const float nxi  = sI[9 * 64 + ii], nyi  = sI[10 * 64 + ii], nzi = sI[11 * 64 + ii];
  const float d1i  = sI[12 * 64 + ii];

  unsigned short* qb = qbuf[w];
  int qtail = 0, qhead = 0;  // wave-uniform (derived from ballots only)

  // Dense drain: nd queued pairs processed by nd lanes, full tail math.
  auto drain = [&](int nd) {
    if (lane < nd) {
      const int e  = qb[(qhead + lane) & 255];
      const int qi = e >> 6;
      const int qj = e & 63;
      const float A0x = sI[0 * 64 + qi], A0y = sI[1 * 64 + qi], A0z = sI[2 * 64 + qi];
      const float A1x = sI[3 * 64 + qi], A1y = sI[4 * 64 + qi], A1z = sI[5 * 64 + qi];
      const float A2x = sI[6 * 64 + qi], A2y = sI[7 * 64 + qi], A2z = sI[8 * 64 + qi];
      const float Anx = sI[9 * 64 + qi], Any = sI[10 * 64 + qi], Anz = sI[11 * 64 + qi];
      const float Ad  = sI[12 * 64 + qi];
      const float B0x = sJ[0 * 64 + qj], B0y = sJ[1 * 64 + qj], B0z = sJ[2 * 64 + qj];
      const float B1x = sJ[3 * 64 + qj], B1y = sJ[4 * 64 + qj], B1z = sJ[5 * 64 + qj];
      const float B2x = sJ[6 * 64 + qj], B2y = sJ[7 * 64 + qj], B2z = sJ[8 * 64 + qj];
      const float Bnx = sJ[9 * 64 + qj], Bny = sJ[10 * 64 + qj], Bnz = sJ[11 * 64 + qj];
      const float Bd  = sJ[12 * 64 + qj];
      // recompute plane distances, identical scalar expressions
      const float dij0 = Anx * B0x + Any * B0y + Anz * B0z + Ad;
      const float dij1 = Anx * B1x + Any * B1y + Anz * B1z + Ad;
      const float dij2 = Anx * B2x + Any * B2y + Anz * B2z + Ad;
      const float dji0 = Bnx * A0x + Bny * A0y + Bnz * A0z + Bd;
      const float dji1 = Bnx * A1x + Bny * A1y + Bnz * A1z + Bd;
      const float dji2 = Bnx * A2x + Bny * A2y + Bnz * A2z + Bd;
      const int kk = vl_tail(A0x, A0y, A0z, A1x, A1y, A1z, A2x, A2y, A2z,
                             Anx, Any, Anz,
                             B0x, B0y, B0z, B1x, B1y, B1z, B2x, B2y, B2z,
                             Bnx, Bny, Bnz,
                             dij0, dij1, dij2, dji0, dji1, dji2,
                             bi + qi, bj + qj);
      if (kk) {
        atomicAdd(&srowI[qi], 1);                       // credit row[i]
        if (!(dg && qi == qj))                          // self-pair: once
          atomicAdd(dg ? &srowI[qj] : &srowJ[qj], 1);   // credit row[j]
      }
    }
    qhead += nd;
  };

  // ---- phase 1: branchless 4-wide packed plane tests (4 x 4 j's) ----
  const unsigned long long lt = (1ULL << lane) - 1ULL;
#pragma unroll 2
  for (int s = 0; s < 4; ++s) {
    const int jj = (w << 2) + (s << 4);   // multiple of 4 -> 16B-aligned

    const f32x4 ju0x = *(const f32x4*)&sJ[0 * 64 + jj];
    const f32x4 ju0y = *(const f32x4*)&sJ[1 * 64 + jj];
    const f32x4 ju0z = *(const f32x4*)&sJ[2 * 64 + jj];
    const f32x4 ju1x = *(const f32x4*)&sJ[3 * 64 + jj];
    const f32x4 ju1y = *(const f32x4*)&sJ[4 * 64 + jj];
    const f32x4 ju1z = *(const f32x4*)&sJ[5 * 64 + jj];
    const f32x4 ju2x = *(const f32x4*)&sJ[6 * 64 + jj];
    const f32x4 ju2y = *(const f32x4*)&sJ[7 * 64 + jj];
    const f32x4 ju2z = *(const f32x4*)&sJ[8 * 64 + jj];
    const f32x4 nxj  = *(const f32x4*)&sJ[9 * 64 + jj];
    const f32x4 nyj  = *(const f32x4*)&sJ[10 * 64 + jj];
    const f32x4 nzj  = *(const f32x4*)&sJ[11 * 64 + jj];
    const f32x4 d1j  = *(const f32x4*)&sJ[12 * 64 + jj];

    // packed plane distances, all 4 j sub-lanes
    const f32x4 dij0 = nxi * ju0x + nyi * ju0y + nzi * ju0z + d1i;
    const f32x4 dij1 = nxi * ju1x + nyi * ju1y + nzi * ju1z + d1i;
    const f32x4 dij2 = nxi * ju2x + nyi * ju2y + nzi * ju2z + d1i;
    const f32x4 dji0 = nxj * iu0x + nyj * iu0y + nzj * iu0z + d1j;
    const f32x4 dji1 = nxj * iu1x + nyj * iu1y + nzj * iu1z + d1j;
    const f32x4 dji2 = nxj * iu2x + nyj * iu2y + nzj * iu2z + d1j;

    // exact monotone form of the all-pos / all-neg tests, both directions
    const f32x4 mnv = __builtin_elementwise_max(
        __builtin_elementwise_min(__builtin_elementwise_min(dij0, dij1), dij2),
        __builtin_elementwise_min(__builtin_elementwise_min(dji0, dji1), dji2));
    const f32x4 mxv = __builtin_elementwise_min(
        __builtin_elementwise_max(__builtin_elementwise_max(dij0, dij1), dij2),
        __builtin_elementwise_max(__builtin_elementwise_max(dji0, dji1), dji2));

    bool sv[4];
#pragma unroll
    for (int q = 0; q < 4; ++q) {
      sv[q] = (mnv[q] + VL_EPS <= 0.0f) && (mxv[q] - VL_EPS >= 0.0f);
      if (dg) sv[q] = sv[q] && (ii <= jj + q);   // diagonal: ii <= jj only
    }

    // pushes in j-order; ring-safety: drain-check after every 2 pushes
    const unsigned long long m0 = __ballot(sv[0]);
    const unsigned long long m1 = __ballot(sv[1]);
    if (m0 | m1) {
      const int n0 = __popcll(m0);
      if (sv[0]) qb[(qtail + __popcll(m0 & lt)) & 255] =
                     (unsigned short)((ii << 6) | jj);
      if (sv[1]) qb[(qtail + n0 + __popcll(m1 & lt)) & 255] =
                     (unsigned short)((ii << 6) | (jj + 1));
      qtail += n0 + __popcll(m1);
      while (qtail - qhead >= 64) drain(64);
    }
    const unsigned long long m2 = __ballot(sv[2]);
    const unsigned long long m3 = __ballot(sv[3]);
    if (m2 | m3) {
      const int n2 = __popcll(m2);
      if (sv[2]) qb[(qtail + __popcll(m2 & lt)) & 255] =
                     (unsigned short)((ii << 6) | (jj + 2));
      if (sv[3]) qb[(qtail + n2 + __popcll(m3 & lt)) & 255] =
                     (unsigned short)((ii << 6) | (jj + 3));
      qtail += n2 + __popcll(m3);
      while (qtail - qhead >= 64) drain(64);
    }
  }
  if (qtail > qhead) drain(qtail - qhead);

  // ---- epilogue: block-local partial loss, fixed-order reduce ----
  __syncthreads();
  float val = 0.0f;
  if (t < 64) {
    // w[f] = x(v0) + 2*x(v2); staged values are 0 for padded faces and
    // srowI is 0 there, so no bounds check needed.
    val = (sI[0 * 64 + t] + 2.0f * sI[6 * 64 + t]) * (float)srowI[t];
  } else if (t < 128 && !dg) {
    const int l = t - 64;
    val = (sJ[0 * 64 + l] + 2.0f * sJ[6 * 64 + l]) * (float)srowJ[l];
  }
  sred[t] = val;
  __syncthreads();
#pragma unroll
  for (int r = 128; r > 0; r >>= 1) {
    if (t < r) sred[t] += sred[t + r];
    __syncthreads();
  }
  if (t == 0) partial[k] = sred[0];
}

// Final fixed-order reduction over per-block partials: loss = (sum)/3.
__global__ __launch_bounds__(256) void vl_reduce(const float* __restrict__ partial,
                                                 int n, float* __restrict__ out) {
  __shared__ float s[256];
  const int t = threadIdx.x;
  float acc = 0.0f;
  for (int b = t; b < n; b += 256) acc += partial[b];
  s[t] = acc;
  __syncthreads();
  for (int r = 128; r > 0; r >>= 1) {
    if (t < r) s[t] += s[t + r];
    __syncthreads();
  }
  if (t == 0) out[0] = s[0] / 3.0f;
}

extern "C" void kernel_launch(void* const* d_in, const int* in_sizes, int n_in,
                              void* d_out, int out_size, void* d_ws, size_t ws_size,
                              hipStream_t stream) {
  const float* verts = (const float*)d_in[0];   // (1, V, 3) f32
  const float* fnorm = (const float*)d_in[1];   // (1, F, 3) f32
  const int*   faces = (const int*)d_in[2];     // (F, 3) int32
  const int F = in_sizes[1] / 3;

  float* partial = (float*)d_ws;                 // nblk floats (no zeroing)

  const int NB = (F + 63) / 64;
  const int nblk = NB * (NB + 1) / 2;            // triangular tile pairs
  vl_pair<<<nblk, 256, 0, stream>>>(verts, fnorm, faces, partial, F);
  vl_reduce<<<1, 256, 0, stream>>>(partial, nblk, (float*)d_out);
}